// Round 8
// baseline (266.009 us; speedup 1.0000x reference)
//
#include <hip/hip_runtime.h>

// B=2, S=2048, H=1024, NUM_HEAD=16, HEAD=64
#define BATCH 2
#define S_LEN 2048
#define HDIM  1024
#define NHEAD 16
#define HD    64
#define NEGBIAS -1e10f
#define NQE   (BATCH * NHEAD * S_LEN)   // 65536 (bh,q) entries

typedef __attribute__((ext_vector_type(8))) _Float16 half8;  // 8 f16 in 4 VGPRs
typedef __attribute__((ext_vector_type(4))) _Float16 half4;  // 4 f16 in 2 VGPRs
typedef __attribute__((ext_vector_type(4))) float   f32x4;   // MFMA C/D frag

// ---------------------------------------------------------------------------
// W pre-convert: fp32 -> fp16, once.  grid.y selects Wq/Wk/Wv.
// ---------------------------------------------------------------------------
__global__ __launch_bounds__(256) void cvt_w(
    const float* __restrict__ Wq, const float* __restrict__ Wk,
    const float* __restrict__ Wv, _Float16* __restrict__ Wf)
{
    const int z = blockIdx.y;
    const float* src = (z == 0) ? Wq : (z == 1) ? Wk : Wv;
    _Float16* dst = Wf + (size_t)z * (HDIM * HDIM);
    size_t i = ((size_t)blockIdx.x * 256 + threadIdx.x) * 8;   // 1M elems / 8
    float4 a0 = *(const float4*)(src + i);
    float4 a1 = *(const float4*)(src + i + 4);
    half8 v;
    v[0] = (_Float16)a0.x; v[1] = (_Float16)a0.y;
    v[2] = (_Float16)a0.z; v[3] = (_Float16)a0.w;
    v[4] = (_Float16)a1.x; v[5] = (_Float16)a1.y;
    v[6] = (_Float16)a1.z; v[7] = (_Float16)a1.w;
    *(half8*)(dst + i) = v;
}

// ---------------------------------------------------------------------------
// Fused projection GEMM (fp16 MFMA): Y = X @ W^T + b.  W pre-converted f16.
// z=0,1 -> write [B,NH,S,HD]; z=2 -> write V transposed [B,NH,HD,S].
// ---------------------------------------------------------------------------
__global__ __launch_bounds__(256) void proj_gemm_f16(
    const float* __restrict__ Xq, const float* __restrict__ Xk,
    const float* __restrict__ Xv, const _Float16* __restrict__ Wf,
    const float* __restrict__ bq, const float* __restrict__ bk,
    const float* __restrict__ bv,
    _Float16* __restrict__ Qb, _Float16* __restrict__ Kb, _Float16* __restrict__ Vtb)
{
    const int z = blockIdx.z;
    const float* X    = (z == 0) ? Xq : (z == 1) ? Xk : Xv;
    const float* bias = (z == 0) ? bq : (z == 1) ? bk : bv;
    const _Float16* Wz = Wf + (size_t)z * (HDIM * HDIM);
    _Float16* Y       = (z == 0) ? Qb : (z == 1) ? Kb : Vtb;

    const int n0 = blockIdx.x * 128;
    const int m0 = blockIdx.y * 128;

    __shared__ __align__(16) _Float16 As[128][40];  // [m][k], pad 40
    __shared__ __align__(16) _Float16 Bs[128][40];  // [n][k]

    const int t    = threadIdx.x;
    const int w    = t >> 6;
    const int lane = t & 63;
    const int quad = lane >> 4;
    const int lc   = lane & 15;
    const int wm   = (w >> 1) * 64;
    const int wn   = (w & 1) * 64;

    const f32x4 fzero = {0.f, 0.f, 0.f, 0.f};
    f32x4 acc[4][4];
#pragma unroll
    for (int i = 0; i < 4; i++)
#pragma unroll
        for (int j = 0; j < 4; j++) acc[i][j] = fzero;

    const int srow = t >> 2;   // 0..63 (two halves: srow, srow+64)
    const int sc   = t & 3;    // 8-elem chunk within the 32-elem k slice

    for (int k0 = 0; k0 < HDIM; k0 += 32) {
#pragma unroll
        for (int half = 0; half < 2; half++) {
            int row = srow + half * 64;
            {   // X: fp32 -> f16 inline
                const float* g = X + (size_t)(m0 + row) * HDIM + k0 + sc * 8;
                float4 a0 = *(const float4*)g;
                float4 a1 = *(const float4*)(g + 4);
                half8 v;
                v[0] = (_Float16)a0.x; v[1] = (_Float16)a0.y;
                v[2] = (_Float16)a0.z; v[3] = (_Float16)a0.w;
                v[4] = (_Float16)a1.x; v[5] = (_Float16)a1.y;
                v[6] = (_Float16)a1.z; v[7] = (_Float16)a1.w;
                *(half8*)&As[row][sc * 8] = v;
            }
            // W: already f16, straight 16B copy
            *(half8*)&Bs[row][sc * 8] =
                *(const half8*)(Wz + (size_t)(n0 + row) * HDIM + k0 + sc * 8);
        }
        __syncthreads();

        half8 af[4], bf[4];
#pragma unroll
        for (int mt = 0; mt < 4; mt++)
            af[mt] = *(const half8*)&As[wm + mt * 16 + lc][quad * 8];
#pragma unroll
        for (int nt = 0; nt < 4; nt++)
            bf[nt] = *(const half8*)&Bs[wn + nt * 16 + lc][quad * 8];
#pragma unroll
        for (int mt = 0; mt < 4; mt++)
#pragma unroll
            for (int nt = 0; nt < 4; nt++)
                acc[mt][nt] = __builtin_amdgcn_mfma_f32_16x16x32_f16(
                    af[mt], bf[nt], acc[mt][nt], 0, 0, 0);
        __syncthreads();
    }

#pragma unroll
    for (int nt = 0; nt < 4; nt++) {
        const int n = n0 + wn + nt * 16 + lc;          // h*64 + d
        const float bv_ = bias[n];
        const int h = n >> 6, d = n & 63;
#pragma unroll
        for (int mt = 0; mt < 4; mt++) {
#pragma unroll
            for (int r = 0; r < 4; r++) {
                const int m = m0 + wm + mt * 16 + quad * 4 + r;   // b*S + s
                const int b = m >> 11, s = m & (S_LEN - 1);
                const int bh = b * NHEAD + h;
                _Float16 val = (_Float16)(acc[mt][nt][r] + bv_);
                if (z == 2)
                    Y[((size_t)bh * HD + d) * S_LEN + s] = val;          // V^T
                else
                    Y[((size_t)bh * S_LEN + s) * HD + d] = val;          // Q,K
            }
        }
    }
}

// ---------------------------------------------------------------------------
// Split-K flash attention: grid (512, 2); blockIdx.y = key-half.
// Each block: 128 q-rows x 1024 keys (16 kt-iters).  Transposed MFMA
// orientation, 32 q/wave (2 B-frag groups) so each K/V LDS read feeds 2 MFMAs.
// Outputs UNNORMALIZED partial O (f16) + m,l (f32) for the combine pass.
// ---------------------------------------------------------------------------
__global__ __launch_bounds__(256) void flash_attn_split(
    const _Float16* __restrict__ Qb, const _Float16* __restrict__ Kb,
    const _Float16* __restrict__ Vtb, const int* __restrict__ mask,
    _Float16* __restrict__ Opart, float* __restrict__ Mpart,
    float* __restrict__ Lpart)
{
    const int qt   = blockIdx.x & 15;    // 16 q-tiles of 128
    const int bh   = blockIdx.x >> 4;    // 0..31
    const int half = blockIdx.y;         // key half: 0 or 1
    const int b    = bh >> 4;
    const int koff = half * (S_LEN / 2); // 0 or 1024

    __shared__ __align__(16) _Float16 Ks [64][72];      // [key][d]
    __shared__ __align__(16) _Float16 Vts[64][72];      // [d][key]
    __shared__ __align__(16) _Float16 Ps [4][32][72];   // per-wave P, [q][key]
    __shared__ float biasS[64];                         // mask bias per key

    const int t    = threadIdx.x;
    const int w    = t >> 6;
    const int lane = t & 63;
    const int quad = lane >> 4;
    const int lc   = lane & 15;

    const _Float16* Kbase = Kb  + (size_t)bh * S_LEN * HD;
    const _Float16* Vbase = Vtb + (size_t)bh * HD * S_LEN;

    // Q B-frags: qg in {0,1}, q-row = qt*128 + w*32 + qg*16 + lc
    half8 qf[2][2];
#pragma unroll
    for (int qg = 0; qg < 2; qg++) {
        const int qrow = qt * 128 + w * 32 + qg * 16 + lc;
#pragma unroll
        for (int s = 0; s < 2; s++)
            qf[qg][s] = *(const half8*)(Qb + ((size_t)bh * S_LEN + qrow) * HD
                                        + s * 32 + quad * 8);
    }

    const f32x4 fzero = {0.f, 0.f, 0.f, 0.f};
    f32x4 o[2][4];                      // O^T per qg: d = nt*16+quad*4+r, q = lc
#pragma unroll
    for (int qg = 0; qg < 2; qg++)
#pragma unroll
        for (int nt = 0; nt < 4; nt++) o[qg][nt] = fzero;
    float mrun[2] = {-3.0e38f, -3.0e38f};
    float lrun[2] = {0.f, 0.f};

    for (int kt = 0; kt < S_LEN / 2; kt += 64) {
        // stage 64x64 K and Vt tiles (512 chunks of 16B each, 2 per thread)
#pragma unroll
        for (int i = 0; i < 2; i++) {
            int c  = t + 256 * i;        // 0..511
            int rr = c >> 3;             // 0..63
            int cc = (c & 7) * 8;        // 0..56
            *(half8*)&Ks[rr][cc] =
                *(const half8*)(Kbase + (size_t)(koff + kt + rr) * HD + cc);
            *(half8*)&Vts[rr][cc] =
                *(const half8*)(Vbase + (size_t)rr * S_LEN + koff + kt + cc);
        }
        if (t < 64) biasS[t] = mask[b * S_LEN + koff + kt + t] ? 0.f : NEGBIAS;
        __syncthreads();

        // S^T = K.Q^T : each kf read feeds both qg MFMAs
        f32x4 scf[2][4];
#pragma unroll
        for (int qg = 0; qg < 2; qg++)
#pragma unroll
            for (int tt = 0; tt < 4; tt++) scf[qg][tt] = fzero;
#pragma unroll
        for (int s = 0; s < 2; s++) {
#pragma unroll
            for (int tt = 0; tt < 4; tt++) {
                half8 kf = *(const half8*)&Ks[tt * 16 + lc][s * 32 + quad * 8];
                scf[0][tt] = __builtin_amdgcn_mfma_f32_16x16x32_f16(kf, qf[0][s], scf[0][tt], 0, 0, 0);
                scf[1][tt] = __builtin_amdgcn_mfma_f32_16x16x32_f16(kf, qf[1][s], scf[1][tt], 0, 0, 0);
            }
        }

        // mask bias: score (tt,r) is key tt*16+quad*4+r
#pragma unroll
        for (int tt = 0; tt < 4; tt++) {
            float4 b4 = *(const float4*)&biasS[tt * 16 + quad * 4];
#pragma unroll
            for (int qg = 0; qg < 2; qg++) {
                scf[qg][tt][0] += b4.x; scf[qg][tt][1] += b4.y;
                scf[qg][tt][2] += b4.z; scf[qg][tt][3] += b4.w;
            }
        }

        // per-lane online softmax, one q-row per (qg, lc)
#pragma unroll
        for (int qg = 0; qg < 2; qg++) {
            float mx = scf[qg][0][0];
#pragma unroll
            for (int tt = 0; tt < 4; tt++)
#pragma unroll
                for (int r = 0; r < 4; r++) mx = fmaxf(mx, scf[qg][tt][r]);
            mx = fmaxf(mx, __shfl_xor(mx, 16));
            mx = fmaxf(mx, __shfl_xor(mx, 32));

            float mn = fmaxf(mrun[qg], mx);
            float al = __expf(mrun[qg] - mn);
            float ls = 0.f;
#pragma unroll
            for (int tt = 0; tt < 4; tt++)
#pragma unroll
                for (int r = 0; r < 4; r++) {
                    float p = __expf(scf[qg][tt][r] - mn);
                    scf[qg][tt][r] = p;
                    ls += p;
                }
            ls += __shfl_xor(ls, 16);
            ls += __shfl_xor(ls, 32);
            lrun[qg] = lrun[qg] * al + ls;
            mrun[qg] = mn;
#pragma unroll
            for (int nt = 0; nt < 4; nt++) {
                o[qg][nt][0] *= al; o[qg][nt][1] *= al;
                o[qg][nt][2] *= al; o[qg][nt][3] *= al;
            }

            // P rows (q-major): Ps[w][qg*16+lc][key], 8B packed writes
#pragma unroll
            for (int tt = 0; tt < 4; tt++) {
                half4 pk;
                pk[0] = (_Float16)scf[qg][tt][0]; pk[1] = (_Float16)scf[qg][tt][1];
                pk[2] = (_Float16)scf[qg][tt][2]; pk[3] = (_Float16)scf[qg][tt][3];
                *(half4*)&Ps[w][qg * 16 + lc][tt * 16 + quad * 4] = pk;
            }
        }

        // O^T += V^T.P^T : each vf read feeds both qg MFMAs
#pragma unroll
        for (int s = 0; s < 2; s++) {
            half8 pf0 = *(const half8*)&Ps[w][lc]     [s * 32 + quad * 8];
            half8 pf1 = *(const half8*)&Ps[w][16 + lc][s * 32 + quad * 8];
#pragma unroll
            for (int nt = 0; nt < 4; nt++) {
                half8 vf = *(const half8*)&Vts[nt * 16 + lc][s * 32 + quad * 8];
                o[0][nt] = __builtin_amdgcn_mfma_f32_16x16x32_f16(vf, pf0, o[0][nt], 0, 0, 0);
                o[1][nt] = __builtin_amdgcn_mfma_f32_16x16x32_f16(vf, pf1, o[1][nt], 0, 0, 0);
            }
        }
        __syncthreads();
    }

    // epilogue: write UNNORMALIZED partial O (f16) + m, l
#pragma unroll
    for (int qg = 0; qg < 2; qg++) {
        const int qrow = qt * 128 + w * 32 + qg * 16 + lc;
        const size_t qe = (size_t)half * NQE + (size_t)bh * S_LEN + qrow;
        if (quad == 0) { Mpart[qe] = mrun[qg]; Lpart[qe] = lrun[qg]; }
#pragma unroll
        for (int nt = 0; nt < 4; nt++) {
            half4 pk;
            pk[0] = (_Float16)o[qg][nt][0]; pk[1] = (_Float16)o[qg][nt][1];
            pk[2] = (_Float16)o[qg][nt][2]; pk[3] = (_Float16)o[qg][nt][3];
            *(half4*)&Opart[qe * HD + nt * 16 + quad * 4] = pk;
        }
    }
}

// ---------------------------------------------------------------------------
// Combine the two key-half partials: out = (w1*O1 + w2*O2)/(w1*l1 + w2*l2).
// One thread per 8 output dims; 2048 blocks x 256 threads.
// ---------------------------------------------------------------------------
__global__ __launch_bounds__(256) void combine_halves(
    const _Float16* __restrict__ Opart, const float* __restrict__ Mpart,
    const float* __restrict__ Lpart, float* __restrict__ out)
{
    const int idx = blockIdx.x * 256 + threadIdx.x;   // 0..524287
    const int dg  = idx & 7;             // 8-elem d group
    const int qe  = idx >> 3;            // bh*S + q
    const int bh  = qe >> 11;
    const int q   = qe & (S_LEN - 1);
    const int b   = bh >> 4;
    const int h   = bh & (NHEAD - 1);

    const float m1 = Mpart[qe],       l1 = Lpart[qe];
    const float m2 = Mpart[NQE + qe], l2 = Lpart[NQE + qe];
    const float M  = fmaxf(m1, m2);
    const float w1 = __expf(m1 - M), w2 = __expf(m2 - M);
    const float inv = 1.f / (w1 * l1 + w2 * l2);

    half8 o1 = *(const half8*)&Opart[(size_t)qe * HD + dg * 8];
    half8 o2 = *(const half8*)&Opart[(size_t)NQE * HD + (size_t)qe * HD + dg * 8];

    float* dst = out + ((size_t)b * S_LEN + q) * HDIM + h * HD + dg * 8;
    float4 r0, r1;
    r0.x = (w1 * (float)o1[0] + w2 * (float)o2[0]) * inv;
    r0.y = (w1 * (float)o1[1] + w2 * (float)o2[1]) * inv;
    r0.z = (w1 * (float)o1[2] + w2 * (float)o2[2]) * inv;
    r0.w = (w1 * (float)o1[3] + w2 * (float)o2[3]) * inv;
    r1.x = (w1 * (float)o1[4] + w2 * (float)o2[4]) * inv;
    r1.y = (w1 * (float)o1[5] + w2 * (float)o2[5]) * inv;
    r1.z = (w1 * (float)o1[6] + w2 * (float)o2[6]) * inv;
    r1.w = (w1 * (float)o1[7] + w2 * (float)o2[7]) * inv;
    *(float4*)dst = r0;
    *(float4*)(dst + 4) = r1;
}

// ---------------------------------------------------------------------------
extern "C" void kernel_launch(void* const* d_in, const int* in_sizes, int n_in,
                              void* d_out, int out_size, void* d_ws, size_t ws_size,
                              hipStream_t stream) {
    const float* query = (const float*)d_in[0];
    const float* key   = (const float*)d_in[1];
    const float* value = (const float*)d_in[2];
    const int*   mask  = (const int*)  d_in[3];
    const float* Wq    = (const float*)d_in[4];
    const float* bq    = (const float*)d_in[5];
    const float* Wk    = (const float*)d_in[6];
    const float* bk    = (const float*)d_in[7];
    const float* Wv    = (const float*)d_in[8];
    const float* bv    = (const float*)d_in[9];
    float* out = (float*)d_out;

    const size_t nElem = (size_t)BATCH * S_LEN * HDIM;          // 4M
    const size_t wElem = (size_t)HDIM * HDIM;                   // 1M
    // ws: Qb(8M) Kb(8M) Vtb(8M) Wf(6M) Opart(16M) Mpart(0.25M) Lpart(0.25M) ~ 47MB
    const size_t need = (3 * nElem + 3 * wElem + 2 * nElem) * sizeof(_Float16)
                      + 4 * (size_t)NQE * sizeof(float);
    if (ws_size < need) return;
    _Float16* Qb    = (_Float16*)d_ws;
    _Float16* Kb    = Qb + nElem;
    _Float16* Vtb   = Kb + nElem;
    _Float16* Wf    = Vtb + nElem;
    _Float16* Opart = Wf + 3 * wElem;
    float*    Mpart = (float*)(Opart + 2 * nElem);
    float*    Lpart = Mpart + 2 * NQE;

    dim3 gcvt(wElem / (256 * 8), 3);                            // (512, 3)
    cvt_w<<<gcvt, 256, 0, stream>>>(Wq, Wk, Wv, Wf);

    dim3 gproj(HDIM / 128, (BATCH * S_LEN) / 128, 3);           // (8, 32, 3)
    proj_gemm_f16<<<gproj, 256, 0, stream>>>(query, key, value, Wf,
                                             bq, bk, bv, Qb, Kb, Vtb);

    dim3 gattn(BATCH * NHEAD * (S_LEN / 128), 2);               // (512, 2)
    flash_attn_split<<<gattn, 256, 0, stream>>>(Qb, Kb, Vtb, mask,
                                                Opart, Mpart, Lpart);

    combine_halves<<<(NQE * 8) / 256, 256, 0, stream>>>(Opart, Mpart, Lpart, out);
}

// Round 9
// 239.649 us; speedup vs baseline: 1.1100x; 1.1100x over previous
//
#include <hip/hip_runtime.h>

// B=2, S=2048, H=1024, NUM_HEAD=16, HEAD=64
#define BATCH 2
#define S_LEN 2048
#define HDIM  1024
#define NHEAD 16
#define HD    64
#define NEGBIAS -1e10f

typedef __attribute__((ext_vector_type(8))) _Float16 half8;  // 8 f16 in 4 VGPRs
typedef __attribute__((ext_vector_type(4))) _Float16 half4;  // 4 f16 in 2 VGPRs
typedef __attribute__((ext_vector_type(4))) float   f32x4;   // MFMA C/D frag

// ---------------------------------------------------------------------------
// Fused projection GEMM (fp16 MFMA): Y = X @ W^T + b, fp32 inputs converted
// inline.  z=0,1 -> [B,NH,S,HD]; z=2 -> V transposed [B,NH,HD,S].
// 128x128 tile, BK=32.  REGISTER-PREFETCH pipeline: tile k+1 is loaded into
// VGPRs while tile k is computed, so global latency overlaps MFMA work.
// ---------------------------------------------------------------------------
__global__ __launch_bounds__(256) void proj_gemm_f16(
    const float* __restrict__ Xq, const float* __restrict__ Wq, const float* __restrict__ bq,
    const float* __restrict__ Xk, const float* __restrict__ Wk, const float* __restrict__ bk,
    const float* __restrict__ Xv, const float* __restrict__ Wv, const float* __restrict__ bv,
    _Float16* __restrict__ Qb, _Float16* __restrict__ Kb, _Float16* __restrict__ Vtb)
{
    const int z = blockIdx.z;
    const float* X    = (z == 0) ? Xq : (z == 1) ? Xk : Xv;
    const float* W    = (z == 0) ? Wq : (z == 1) ? Wk : Wv;
    const float* bias = (z == 0) ? bq : (z == 1) ? bk : bv;
    _Float16* Y       = (z == 0) ? Qb : (z == 1) ? Kb : Vtb;

    const int n0 = blockIdx.x * 128;
    const int m0 = blockIdx.y * 128;

    __shared__ __align__(16) _Float16 As[128][40];  // [m][k], pad 40
    __shared__ __align__(16) _Float16 Bs[128][40];  // [n][k]

    const int t    = threadIdx.x;
    const int w    = t >> 6;
    const int lane = t & 63;
    const int quad = lane >> 4;
    const int lc   = lane & 15;
    const int wm   = (w >> 1) * 64;
    const int wn   = (w & 1) * 64;

    const f32x4 fzero = {0.f, 0.f, 0.f, 0.f};
    f32x4 acc[4][4];
#pragma unroll
    for (int i = 0; i < 4; i++)
#pragma unroll
        for (int j = 0; j < 4; j++) acc[i][j] = fzero;

    const int srow = t >> 2;   // 0..63 (two halves: srow, srow+64)
    const int sc   = t & 3;    // 8-elem chunk within the 32-elem k slice

    float4 xa[2][2], wa[2][2];          // prefetch registers
#define PROJ_ISSUE(K0)                                                        \
    {                                                                         \
        _Pragma("unroll")                                                     \
        for (int hf = 0; hf < 2; hf++) {                                      \
            const float* gx = X + (size_t)(m0 + srow + hf * 64) * HDIM + (K0) + sc * 8; \
            xa[hf][0] = *(const float4*)gx;                                   \
            xa[hf][1] = *(const float4*)(gx + 4);                             \
            const float* gw = W + (size_t)(n0 + srow + hf * 64) * HDIM + (K0) + sc * 8; \
            wa[hf][0] = *(const float4*)gw;                                   \
            wa[hf][1] = *(const float4*)(gw + 4);                             \
        }                                                                     \
    }

    PROJ_ISSUE(0)

    for (int k0 = 0; k0 < HDIM; k0 += 32) {
        if (k0) __syncthreads();        // prev iter done reading LDS
        // store prefetched tile (fp32 -> f16)
#pragma unroll
        for (int hf = 0; hf < 2; hf++) {
            int row = srow + hf * 64;
            half8 vx;
            vx[0] = (_Float16)xa[hf][0].x; vx[1] = (_Float16)xa[hf][0].y;
            vx[2] = (_Float16)xa[hf][0].z; vx[3] = (_Float16)xa[hf][0].w;
            vx[4] = (_Float16)xa[hf][1].x; vx[5] = (_Float16)xa[hf][1].y;
            vx[6] = (_Float16)xa[hf][1].z; vx[7] = (_Float16)xa[hf][1].w;
            *(half8*)&As[row][sc * 8] = vx;
            half8 vw;
            vw[0] = (_Float16)wa[hf][0].x; vw[1] = (_Float16)wa[hf][0].y;
            vw[2] = (_Float16)wa[hf][0].z; vw[3] = (_Float16)wa[hf][0].w;
            vw[4] = (_Float16)wa[hf][1].x; vw[5] = (_Float16)wa[hf][1].y;
            vw[6] = (_Float16)wa[hf][1].z; vw[7] = (_Float16)wa[hf][1].w;
            *(half8*)&Bs[row][sc * 8] = vw;
        }
        __syncthreads();

        if (k0 + 32 < HDIM) PROJ_ISSUE(k0 + 32)   // overlap with MFMAs below

        half8 af[4], bf[4];
#pragma unroll
        for (int mt = 0; mt < 4; mt++)
            af[mt] = *(const half8*)&As[wm + mt * 16 + lc][quad * 8];
#pragma unroll
        for (int nt = 0; nt < 4; nt++)
            bf[nt] = *(const half8*)&Bs[wn + nt * 16 + lc][quad * 8];
#pragma unroll
        for (int mt = 0; mt < 4; mt++)
#pragma unroll
            for (int nt = 0; nt < 4; nt++)
                acc[mt][nt] = __builtin_amdgcn_mfma_f32_16x16x32_f16(
                    af[mt], bf[nt], acc[mt][nt], 0, 0, 0);
    }

#pragma unroll
    for (int nt = 0; nt < 4; nt++) {
        const int n = n0 + wn + nt * 16 + lc;          // h*64 + d
        const float bv_ = bias[n];
        const int h = n >> 6, d = n & 63;
#pragma unroll
        for (int mt = 0; mt < 4; mt++) {
#pragma unroll
            for (int r = 0; r < 4; r++) {
                const int m = m0 + wm + mt * 16 + quad * 4 + r;   // b*S + s
                const int b = m >> 11, s = m & (S_LEN - 1);
                const int bh = b * NHEAD + h;
                _Float16 val = (_Float16)(acc[mt][nt][r] + bv_);
                if (z == 2)
                    Y[((size_t)bh * HD + d) * S_LEN + s] = val;          // V^T
                else
                    Y[((size_t)bh * S_LEN + s) * HD + d] = val;          // Q,K
            }
        }
    }
}

// ---------------------------------------------------------------------------
// Flash attention (R6 structure + register prefetch).  Transposed MFMA
// orientation (S^T = K.Q^T, O^T = V^T.P^T), 32 q/wave (2 B-frag groups) so
// each K/V LDS read feeds 2 MFMAs.  Block = 128 q-rows, 4 waves, full key seq.
// K/V tile kt+1 is prefetched into VGPRs while tile kt is computed.
// ---------------------------------------------------------------------------
__global__ __launch_bounds__(256) void flash_attn_mfma(
    const _Float16* __restrict__ Qb, const _Float16* __restrict__ Kb,
    const _Float16* __restrict__ Vtb, const int* __restrict__ mask,
    float* __restrict__ out)
{
    const int qt = blockIdx.x & 15;      // 16 q-tiles of 128
    const int bh = blockIdx.x >> 4;      // 0..31
    const int b  = bh >> 4;
    const int h  = bh & (NHEAD - 1);

    __shared__ __align__(16) _Float16 Ks [64][72];      // [key][d]
    __shared__ __align__(16) _Float16 Vts[64][72];      // [d][key]
    __shared__ __align__(16) _Float16 Ps [4][32][72];   // per-wave P, [q][key]
    __shared__ float biasS[64];                         // mask bias per key

    const int t    = threadIdx.x;
    const int w    = t >> 6;
    const int lane = t & 63;
    const int quad = lane >> 4;
    const int lc   = lane & 15;

    const _Float16* Kbase = Kb  + (size_t)bh * S_LEN * HD;
    const _Float16* Vbase = Vtb + (size_t)bh * HD * S_LEN;
    const int* mbase = mask + b * S_LEN;

    // Q B-frags: qg in {0,1}, q-row = qt*128 + w*32 + qg*16 + lc
    half8 qf[2][2];
#pragma unroll
    for (int qg = 0; qg < 2; qg++) {
        const int qrow = qt * 128 + w * 32 + qg * 16 + lc;
#pragma unroll
        for (int s = 0; s < 2; s++)
            qf[qg][s] = *(const half8*)(Qb + ((size_t)bh * S_LEN + qrow) * HD
                                        + s * 32 + quad * 8);
    }

    const f32x4 fzero = {0.f, 0.f, 0.f, 0.f};
    f32x4 o[2][4];                      // O^T per qg: d = nt*16+quad*4+r, q = lc
#pragma unroll
    for (int qg = 0; qg < 2; qg++)
#pragma unroll
        for (int nt = 0; nt < 4; nt++) o[qg][nt] = fzero;
    float mrun[2] = {-3.0e38f, -3.0e38f};
    float lrun[2] = {0.f, 0.f};

    // staging geometry: chunk c = t + 256*i -> row c>>3, col (c&7)*8
    const int rr0 = t >> 3,          cc0 = (t & 7) * 8;
    const int rr1 = (t + 256) >> 3,  cc1 = (t & 7) * 8;   // (t+256)&7 == t&7

    half8 kpre[2], vpre[2];
    int   mpre;
#define ATTN_ISSUE(KT)                                                        \
    {                                                                         \
        kpre[0] = *(const half8*)(Kbase + (size_t)((KT) + rr0) * HD + cc0);   \
        kpre[1] = *(const half8*)(Kbase + (size_t)((KT) + rr1) * HD + cc1);   \
        vpre[0] = *(const half8*)(Vbase + (size_t)rr0 * S_LEN + (KT) + cc0);  \
        vpre[1] = *(const half8*)(Vbase + (size_t)rr1 * S_LEN + (KT) + cc1);  \
        mpre    = mbase[(KT) + (t & 63)];                                     \
    }

    ATTN_ISSUE(0)

    for (int kt = 0; kt < S_LEN; kt += 64) {
        if (kt) __syncthreads();        // prev iter done reading LDS
        *(half8*)&Ks [rr0][cc0] = kpre[0];
        *(half8*)&Ks [rr1][cc1] = kpre[1];
        *(half8*)&Vts[rr0][cc0] = vpre[0];
        *(half8*)&Vts[rr1][cc1] = vpre[1];
        if (t < 64) biasS[t] = mpre ? 0.f : NEGBIAS;
        __syncthreads();

        if (kt + 64 < S_LEN) ATTN_ISSUE(kt + 64)   // overlap with compute

        // S^T = K.Q^T : each kf read feeds both qg MFMAs
        f32x4 scf[2][4];
#pragma unroll
        for (int qg = 0; qg < 2; qg++)
#pragma unroll
            for (int tt = 0; tt < 4; tt++) scf[qg][tt] = fzero;
#pragma unroll
        for (int s = 0; s < 2; s++) {
#pragma unroll
            for (int tt = 0; tt < 4; tt++) {
                half8 kf = *(const half8*)&Ks[tt * 16 + lc][s * 32 + quad * 8];
                scf[0][tt] = __builtin_amdgcn_mfma_f32_16x16x32_f16(kf, qf[0][s], scf[0][tt], 0, 0, 0);
                scf[1][tt] = __builtin_amdgcn_mfma_f32_16x16x32_f16(kf, qf[1][s], scf[1][tt], 0, 0, 0);
            }
        }

        // mask bias: score (tt,r) is key tt*16+quad*4+r
#pragma unroll
        for (int tt = 0; tt < 4; tt++) {
            float4 b4 = *(const float4*)&biasS[tt * 16 + quad * 4];
#pragma unroll
            for (int qg = 0; qg < 2; qg++) {
                scf[qg][tt][0] += b4.x; scf[qg][tt][1] += b4.y;
                scf[qg][tt][2] += b4.z; scf[qg][tt][3] += b4.w;
            }
        }

        // per-lane online softmax, one q-row per (qg, lc)
#pragma unroll
        for (int qg = 0; qg < 2; qg++) {
            float mx = scf[qg][0][0];
#pragma unroll
            for (int tt = 0; tt < 4; tt++)
#pragma unroll
                for (int r = 0; r < 4; r++) mx = fmaxf(mx, scf[qg][tt][r]);
            mx = fmaxf(mx, __shfl_xor(mx, 16));
            mx = fmaxf(mx, __shfl_xor(mx, 32));

            float mn = fmaxf(mrun[qg], mx);
            float al = __expf(mrun[qg] - mn);
            float ls = 0.f;
#pragma unroll
            for (int tt = 0; tt < 4; tt++)
#pragma unroll
                for (int r = 0; r < 4; r++) {
                    float p = __expf(scf[qg][tt][r] - mn);
                    scf[qg][tt][r] = p;
                    ls += p;
                }
            ls += __shfl_xor(ls, 16);
            ls += __shfl_xor(ls, 32);
            lrun[qg] = lrun[qg] * al + ls;
            mrun[qg] = mn;
#pragma unroll
            for (int nt = 0; nt < 4; nt++) {
                o[qg][nt][0] *= al; o[qg][nt][1] *= al;
                o[qg][nt][2] *= al; o[qg][nt][3] *= al;
            }

            // P rows (q-major): Ps[w][qg*16+lc][key], 8B packed writes
#pragma unroll
            for (int tt = 0; tt < 4; tt++) {
                half4 pk;
                pk[0] = (_Float16)scf[qg][tt][0]; pk[1] = (_Float16)scf[qg][tt][1];
                pk[2] = (_Float16)scf[qg][tt][2]; pk[3] = (_Float16)scf[qg][tt][3];
                *(half4*)&Ps[w][qg * 16 + lc][tt * 16 + quad * 4] = pk;
            }
        }

        // O^T += V^T.P^T : each vf read feeds both qg MFMAs
#pragma unroll
        for (int s = 0; s < 2; s++) {
            half8 pf0 = *(const half8*)&Ps[w][lc]     [s * 32 + quad * 8];
            half8 pf1 = *(const half8*)&Ps[w][16 + lc][s * 32 + quad * 8];
#pragma unroll
            for (int nt = 0; nt < 4; nt++) {
                half8 vf = *(const half8*)&Vts[nt * 16 + lc][s * 32 + quad * 8];
                o[0][nt] = __builtin_amdgcn_mfma_f32_16x16x32_f16(vf, pf0, o[0][nt], 0, 0, 0);
                o[1][nt] = __builtin_amdgcn_mfma_f32_16x16x32_f16(vf, pf1, o[1][nt], 0, 0, 0);
            }
        }
    }

    // epilogue: lane owns q-row per qg; contiguous float4 stores
#pragma unroll
    for (int qg = 0; qg < 2; qg++) {
        const int qrow = qt * 128 + w * 32 + qg * 16 + lc;
        const float inv = 1.f / lrun[qg];
        const size_t rowb = ((size_t)b * S_LEN + qrow) * HDIM + h * HD;
#pragma unroll
        for (int nt = 0; nt < 4; nt++) {
            float4 v;
            v.x = o[qg][nt][0] * inv; v.y = o[qg][nt][1] * inv;
            v.z = o[qg][nt][2] * inv; v.w = o[qg][nt][3] * inv;
            *(float4*)&out[rowb + nt * 16 + quad * 4] = v;
        }
    }
}

// ---------------------------------------------------------------------------
extern "C" void kernel_launch(void* const* d_in, const int* in_sizes, int n_in,
                              void* d_out, int out_size, void* d_ws, size_t ws_size,
                              hipStream_t stream) {
    const float* query = (const float*)d_in[0];
    const float* key   = (const float*)d_in[1];
    const float* value = (const float*)d_in[2];
    const int*   mask  = (const int*)  d_in[3];
    const float* Wq    = (const float*)d_in[4];
    const float* bq    = (const float*)d_in[5];
    const float* Wk    = (const float*)d_in[6];
    const float* bk    = (const float*)d_in[7];
    const float* Wv    = (const float*)d_in[8];
    const float* bv    = (const float*)d_in[9];
    float* out = (float*)d_out;

    const size_t nElem = (size_t)BATCH * S_LEN * HDIM;          // 4M
    if (ws_size < 3 * nElem * sizeof(_Float16)) return;         // 24 MB
    _Float16* Qb  = (_Float16*)d_ws;
    _Float16* Kb  = Qb + nElem;
    _Float16* Vtb = Kb + nElem;

    dim3 gproj(HDIM / 128, (BATCH * S_LEN) / 128, 3);           // (8, 32, 3)
    proj_gemm_f16<<<gproj, 256, 0, stream>>>(query, Wq, bq, key, Wk, bk,
                                             value, Wv, bv, Qb, Kb, Vtb);

    flash_attn_mfma<<<BATCH * NHEAD * (S_LEN / 128), 256, 0, stream>>>(
        Qb, Kb, Vtb, mask, out);
}